// Round 1
// 1045.104 us; speedup vs baseline: 1.5308x; 1.5308x over previous
//
#include <hip/hip_runtime.h>
#include <hip/hip_bf16.h>
#include <math.h>

constexpr int B  = 2;
constexpr int S  = 2048;
constexpr int D  = 1024;
constexpr int H  = 16;
constexpr int DK = 64;   // == DV
constexpr float SCALE = 0.125f;  // 1/sqrt(64)

typedef __attribute__((ext_vector_type(8))) short bf16x8;   // 8 bf16 = 4 VGPRs
typedef __attribute__((ext_vector_type(4))) short s16x4;
typedef __attribute__((ext_vector_type(4))) float f32x4;
typedef __attribute__((ext_vector_type(4))) int   i32x4;

__device__ inline short f2bf(float x) {
    __hip_bfloat16 h = __float2bfloat16(x);
    return *reinterpret_cast<short*>(&h);
}

// async global->LDS, 16B per lane. LDS dest = wave-uniform base + lane*16.
__device__ inline void gload_lds16(const short* g, short* l) {
    __builtin_amdgcn_global_load_lds(
        (const __attribute__((address_space(1))) void*)g,
        (__attribute__((address_space(3))) void*)l, 16, 0, 0);
}

// ---------------------------------------------------------------------------
// f32 -> bf16 vectorized convert (8 elem / thread)
// ---------------------------------------------------------------------------
__global__ __launch_bounds__(256)
void cvt_bf16(const float* __restrict__ src, short* __restrict__ dst, int n)
{
    const int i = (blockIdx.x * 256 + threadIdx.x) * 8;
    if (i >= n) return;
    const float4 a = *(const float4*)(src + i);
    const float4 b = *(const float4*)(src + i + 4);
    bf16x8 o;
    o[0] = f2bf(a.x); o[1] = f2bf(a.y); o[2] = f2bf(a.z); o[3] = f2bf(a.w);
    o[4] = f2bf(b.x); o[5] = f2bf(b.y); o[6] = f2bf(b.z); o[7] = f2bf(b.w);
    *(bf16x8*)(dst + i) = o;
}

// ---------------------------------------------------------------------------
// bf16 MFMA GEMM, m97 structure: 128x128 tile, BK=32, 4 waves (2x2),
// each wave 4x4 frags of 16x16x32.  C = Ab @ Wb^T + bias.
// Ab: [M,K] bf16 row-major, Wb: [N,K] bf16 row-major.
// MODE 0: f32 row-major [M,N].
// MODE 1: bf16 scatter to [B,H,S,64], value*scale.
// MODE 2: bf16 scatter transposed [B,H,64,S].
// ---------------------------------------------------------------------------
template<int MODE>
__global__ __launch_bounds__(256)
void gemm_mfma(const short* __restrict__ Ab, const short* __restrict__ Wb,
               const float* __restrict__ bias, void* __restrict__ Cout,
               int M, int N, int K, float scale)
{
    __shared__ short As[128 * 32];
    __shared__ short Bs[128 * 32];

    const int tid  = threadIdx.x;
    const int lane = tid & 63;
    const int wave = tid >> 6;
    const int l15  = lane & 15;
    const int quad = lane >> 4;
    const int wm   = wave >> 1;
    const int wn   = wave & 1;
    const int m0   = blockIdx.y * 128;
    const int n0   = blockIdx.x * 128;

    // staging: thread t -> row t>>2 (0..63), col-chunk (t&3)*8; linear LDS
    const int srow = tid >> 2;
    const int scol = (tid & 3) * 8;
    const short* ga = Ab + (size_t)(m0 + srow) * K + scol;
    const short* gb = Wb + (size_t)(n0 + srow) * K + scol;
    short* la = As + wave * (16 * 32);
    short* lb = Bs + wave * (16 * 32);
    const size_t rstep = (size_t)64 * K;

    f32x4 acc[4][4] = {};

    for (int k0 = 0; k0 < K; k0 += 32) {
        __syncthreads();                    // readers of prev tile done
        gload_lds16(ga,         la);
        gload_lds16(ga + rstep, la + 64 * 32);
        gload_lds16(gb,         lb);
        gload_lds16(gb + rstep, lb + 64 * 32);
        ga += 32; gb += 32;
        __syncthreads();                    // vmcnt(0) drain -> LDS valid

        bf16x8 af[4], bf[4];
        #pragma unroll
        for (int mi = 0; mi < 4; ++mi)
            af[mi] = *(const bf16x8*)&As[(wm * 64 + mi * 16 + l15) * 32 + quad * 8];
        #pragma unroll
        for (int ni = 0; ni < 4; ++ni)
            bf[ni] = *(const bf16x8*)&Bs[(wn * 64 + ni * 16 + l15) * 32 + quad * 8];
        #pragma unroll
        for (int mi = 0; mi < 4; ++mi)
            #pragma unroll
            for (int ni = 0; ni < 4; ++ni)
                acc[mi][ni] = __builtin_amdgcn_mfma_f32_16x16x32_bf16(
                                  af[mi], bf[ni], acc[mi][ni], 0, 0, 0);
    }

    // epilogue: C-frag row = m (A-row) = quad*4+r, col = n (W-row) = l15
    const int mbase = m0 + wm * 64;
    const int nbase = n0 + wn * 64;
    #pragma unroll
    for (int ni = 0; ni < 4; ++ni) {
        const int n  = nbase + ni * 16 + l15;
        const float bn = bias[n];
        #pragma unroll
        for (int mi = 0; mi < 4; ++mi) {
            const int mr0 = mbase + mi * 16 + quad * 4;
            f32x4 c = acc[mi][ni];
            if (MODE == 0) {
                #pragma unroll
                for (int r = 0; r < 4; ++r)
                    ((float*)Cout)[(size_t)(mr0 + r) * N + n] = c[r] + bn;
            } else if (MODE == 1) {
                const int hh = n >> 6, dd = n & 63;
                #pragma unroll
                for (int r = 0; r < 4; ++r) {
                    const int m  = mr0 + r;
                    const int bb = m >> 11, ss = m & (S - 1);
                    ((short*)Cout)[(((size_t)(bb * H + hh) * S + ss) << 6) + dd] =
                        f2bf((c[r] + bn) * scale);
                }
            } else {  // MODE 2: [B,H,64,S]; r-consecutive -> s-consecutive
                const int hh = n >> 6, dd = n & 63;
                const int bb = mr0 >> 11, ss = mr0 & (S - 1);
                s16x4 ov;
                #pragma unroll
                for (int r = 0; r < 4; ++r) ov[r] = f2bf((c[r] + bn) * scale);
                *(s16x4*)&((short*)Cout)[((size_t)(bb * H + hh) * 64 + dd) * S + ss] = ov;
            }
        }
    }
}

// ---------------------------------------------------------------------------
// Flash attention, SWAPPED-operand QK^T:  S^T = mfma(K, Q)
//   -> C-frag: row = t (quad*4+r within 16-blk), col = q (l15).
// Per-lane scores are contiguous in t => prev is 4x float4, mask 4x int4,
// softmax reductions are lane-local + 2 shuffles (over quad).
// PV: O^T = mfma(V^T, P)  (V^T from Vt [B,H,64,S]; P[q][t] via wave-private
// LDS bounce).  Epilogue writes Ao as bf16 [B,S,H*64].
// ---------------------------------------------------------------------------
__global__ __launch_bounds__(256, 4)
void attn_mfma(const short* __restrict__ Qb, const short* __restrict__ Kb,
               const short* __restrict__ Vt, const float* __restrict__ prev,
               const int*  __restrict__ mask, short* __restrict__ Ao)
{
    __shared__ short Pt[4][16][72];   // per-wave P[q][t] tile, +8 pad

    const int tid  = threadIdx.x;
    const int wave = tid >> 6;
    const int lane = tid & 63;
    const int l15  = lane & 15;
    const int quad = lane >> 4;

    const int bh = blockIdx.x >> 5;       // 32 q-tiles per (b,h)
    const int qt = blockIdx.x & 31;
    const int b  = bh >> 4;
    const int h  = bh & 15;
    const int q0 = qt * 64 + wave * 16;   // this wave's 16 q-rows

    const size_t bhS = (size_t)bh * S;

    // Q as B-operand frag: q = l15, k = quad*8+j (+32)
    bf16x8 qf0, qf1;
    {
        const short* qrow = Qb + ((bhS + q0 + l15) << 6) + quad * 8;
        qf0 = *(const bf16x8*)(qrow);
        qf1 = *(const bf16x8*)(qrow + 32);
    }

    const float* prow  = prev + (bhS + q0 + l15) * S;     // lane's q-row of prev
    const int*   mrow  = mask + b * S;
    const short* kbase = Kb + ((bhS + l15) << 6) + quad * 8;
    const short* vbase = Vt + ((size_t)bh * 64 + l15) * S + quad * 8;

    f32x4 o[4] = {};              // O^T frags: row=d-local, col=q=l15
    float m_i = -INFINITY, l_i = 0.f;

    for (int t0 = 0; t0 < S; t0 += 64) {
        // prefetch prev + mask for this tile (contiguous in t per lane)
        f32x4 pv[4]; i32x4 mk[4];
        #pragma unroll
        for (int nb = 0; nb < 4; ++nb) {
            pv[nb] = *(const f32x4*)(prow + t0 + nb * 16 + quad * 4);
            mk[nb] = *(const i32x4*)(mrow + t0 + nb * 16 + quad * 4);
        }

        // ---- S^T = K·Q^T ----
        f32x4 sfr[4] = {};
        #pragma unroll
        for (int nb = 0; nb < 4; ++nb) {
            const short* krow = kbase + ((size_t)(t0 + nb * 16) << 6);
            bf16x8 kf0 = *(const bf16x8*)(krow);
            bf16x8 kf1 = *(const bf16x8*)(krow + 32);
            sfr[nb] = __builtin_amdgcn_mfma_f32_16x16x32_bf16(kf0, qf0, sfr[nb], 0, 0, 0);
            sfr[nb] = __builtin_amdgcn_mfma_f32_16x16x32_bf16(kf1, qf1, sfr[nb], 0, 0, 0);
        }

        // ---- + prev, mask, row-max (lane-local then 2 shuffles) ----
        float tmax = -INFINITY;
        #pragma unroll
        for (int nb = 0; nb < 4; ++nb)
            #pragma unroll
            for (int r = 0; r < 4; ++r) {
                float sv = sfr[nb][r] + pv[nb][r];
                sv = mk[nb][r] ? -1e30f : sv;
                sfr[nb][r] = sv;
                tmax = fmaxf(tmax, sv);
            }
        tmax = fmaxf(tmax, __shfl_xor(tmax, 16, 64));
        tmax = fmaxf(tmax, __shfl_xor(tmax, 32, 64));

        const float mnew  = fmaxf(m_i, tmax);
        const float alpha = __expf(m_i - mnew);
        m_i = mnew;

        // ---- P = exp(S - m), store [q][t] to LDS (4x ds_write_b64) ----
        float psum = 0.f;
        #pragma unroll
        for (int nb = 0; nb < 4; ++nb) {
            s16x4 pk;
            #pragma unroll
            for (int r = 0; r < 4; ++r) {
                const float e = __expf(sfr[nb][r] - m_i);
                psum += e;
                pk[r] = f2bf(e);
            }
            *(s16x4*)&Pt[wave][l15][nb * 16 + quad * 4] = pk;
        }
        psum += __shfl_xor(psum, 16, 64);
        psum += __shfl_xor(psum, 32, 64);
        l_i = l_i * alpha + psum;

        #pragma unroll
        for (int nv = 0; nv < 4; ++nv) o[nv] *= alpha;

        // wave-private LDS write->read: drain LDS only, no barrier
        __asm__ __volatile__("s_waitcnt lgkmcnt(0)" ::: "memory");

        // ---- O^T += V^T · P^T ----
        bf16x8 pf0 = *(const bf16x8*)&Pt[wave][l15][quad * 8];
        bf16x8 pf1 = *(const bf16x8*)&Pt[wave][l15][32 + quad * 8];
        #pragma unroll
        for (int nv = 0; nv < 4; ++nv) {
            const short* vrow = vbase + (size_t)(nv * 16) * S + t0;
            bf16x8 vf0 = *(const bf16x8*)(vrow);
            bf16x8 vf1 = *(const bf16x8*)(vrow + 32);
            o[nv] = __builtin_amdgcn_mfma_f32_16x16x32_bf16(vf0, pf0, o[nv], 0, 0, 0);
            o[nv] = __builtin_amdgcn_mfma_f32_16x16x32_bf16(vf1, pf1, o[nv], 0, 0, 0);
        }
    }

    // ---- epilogue: /l, bf16 store Ao[b, q, h*64 + d], 4 contiguous d per store
    const float invl = 1.f / l_i;
    const int   srow = q0 + l15;
    #pragma unroll
    for (int nv = 0; nv < 4; ++nv) {
        s16x4 ov;
        #pragma unroll
        for (int r = 0; r < 4; ++r) ov[r] = f2bf(o[nv][r] * invl);
        *(s16x4*)&Ao[((size_t)(b * S + srow)) * D + h * 64 + nv * 16 + quad * 4] = ov;
    }
}

// ---------------------------------------------------------------------------
extern "C" void kernel_launch(void* const* d_in, const int* in_sizes, int n_in,
                              void* d_out, int out_size, void* d_ws, size_t ws_size,
                              hipStream_t stream)
{
    const float* q    = (const float*)d_in[0];
    const float* k    = (const float*)d_in[1];
    const float* v    = (const float*)d_in[2];
    const float* prev = (const float*)d_in[3];
    const int*   mask = (const int*)  d_in[4];
    const float* Wq   = (const float*)d_in[5];
    const float* bq   = (const float*)d_in[6];
    const float* Wk   = (const float*)d_in[7];
    const float* bk   = (const float*)d_in[8];
    const float* Wv   = (const float*)d_in[9];
    const float* bv   = (const float*)d_in[10];
    const float* Wo   = (const float*)d_in[11];
    const float* bo   = (const float*)d_in[12];
    float* out = (float*)d_out;

    const int perBuf = B * H * S * 64;          // 4,194,304 elems
    const int nA = B * S * D;                   // 4,194,304 (== perBuf)
    const int nW = D * D;                       // 1,048,576

    short* Qb   = (short*)d_ws;                 // 8 MB bf16 [B,H,S,64] (pre-scaled)
    short* Kb   = Qb + perBuf;                  // 8 MB
    short* Vt   = Kb + perBuf;                  // 8 MB [B,H,64,S]
    short* Ao   = Vt + perBuf;                  // 8 MB bf16 [B*S, D]; doubles as Abuf
    short* Wbuf = Ao + perBuf;                  // 2 MB bf16 [1024,1024]
    short* Abuf = Ao;                           // alias (free before attn writes Ao)
    // total ws: 34 MB

    dim3 cb(256);
    dim3 gg(D / 128, (B * S) / 128);            // 8 x 32 = 256 blocks

    cvt_bf16<<<nA / 2048, cb, 0, stream>>>(q,  Abuf, nA);
    cvt_bf16<<<nW / 2048, cb, 0, stream>>>(Wq, Wbuf, nW);
    gemm_mfma<1><<<gg, cb, 0, stream>>>(Abuf, Wbuf, bq, Qb, B * S, H * DK, D, SCALE);

    cvt_bf16<<<nA / 2048, cb, 0, stream>>>(k,  Abuf, nA);
    cvt_bf16<<<nW / 2048, cb, 0, stream>>>(Wk, Wbuf, nW);
    gemm_mfma<1><<<gg, cb, 0, stream>>>(Abuf, Wbuf, bk, Kb, B * S, H * DK, D, 1.0f);

    cvt_bf16<<<nA / 2048, cb, 0, stream>>>(v,  Abuf, nA);
    cvt_bf16<<<nW / 2048, cb, 0, stream>>>(Wv, Wbuf, nW);
    gemm_mfma<2><<<gg, cb, 0, stream>>>(Abuf, Wbuf, bv, Vt, B * S, H * DK, D, 1.0f);

    attn_mfma<<<dim3(B * H * (S / 64)), cb, 0, stream>>>(Qb, Kb, Vt, prev, mask, Ao);

    cvt_bf16<<<nW / 2048, cb, 0, stream>>>(Wo, Wbuf, nW);
    gemm_mfma<0><<<gg, cb, 0, stream>>>(Ao, Wbuf, bo, out, B * S, D, H * DK, 1.0f);
}